// Round 9
// baseline (354.358 us; speedup 1.0000x reference)
//
#include <hip/hip_runtime.h>

// Mixture-of-Experts, sparse top-2.
// Round 9: 256x256 8-phase counted-vmcnt grouped GEMM (BK=32, 4-slot LDS ring,
// 512 thr / 8 waves), expert->XCD pinning, persistent tile lists.
// Fast transpose64 prep for W1+W2, single-block route, LN1, combine.

#define E_N 8
#define TOPK 2
#define DM 1024
#define FF 4096
#define NTOK 4096
#define NA 8192
#define LN_EPS 1e-5f

typedef __attribute__((ext_vector_type(4))) float f32x4;
typedef __attribute__((ext_vector_type(8))) short short8;

__device__ __forceinline__ unsigned short f2bf(float f) {
    unsigned int u = __builtin_bit_cast(unsigned int, f);
    u = (u + 0x7FFFu + ((u >> 16) & 1u)) >> 16;   // RNE
    return (unsigned short)u;
}
__device__ __forceinline__ float bf2f(unsigned short h) {
    unsigned int u = ((unsigned int)h) << 16;
    return __builtin_bit_cast(float, u);
}
__device__ __forceinline__ void unp(unsigned int u, float& lo, float& hi) {
    lo = bf2f((unsigned short)(u & 0xffffu));
    hi = bf2f((unsigned short)(u >> 16));
}
__device__ __forceinline__ unsigned int pk(float lo, float hi) {
    return (unsigned int)f2bf(lo) | ((unsigned int)f2bf(hi) << 16);
}

__device__ __forceinline__ void gload16(const unsigned short* g, char* lds) {
    __builtin_amdgcn_global_load_lds(
        (const __attribute__((address_space(1))) unsigned int*)g,
        (__attribute__((address_space(3))) unsigned int*)lds, 16, 0, 0);
}

// ---- 64x64 f32 -> bf16 transpose via swizzled LDS (conflict-free both phases)
__device__ __forceinline__ void transpose64(const float* __restrict__ s, int sld,
                                            unsigned short* __restrict__ d, int dld,
                                            float* tile) {
    int tid = threadIdx.x;
    int lr = tid >> 4, lc = (tid & 15) * 4;
#pragma unroll
    for (int p = 0; p < 4; p++) {
        int r = lr + p * 16;
        float4 v = *(const float4*)(s + (size_t)r * sld + lc);
        *(float4*)&tile[r * 64 + (lc ^ (((r >> 3) & 7) << 2))] = v;
    }
    __syncthreads();
    int a = tid & 7;          // row-block (8 rows)
    int col = (tid >> 3) * 2; // output row pair
    int cbase = (col & ~3) ^ (a << 2);
    int clo = col & 3;
    unsigned int o0[4], o1[4];
#pragma unroll
    for (int i = 0; i < 8; i += 2) {
        int r0 = 8 * a + i;
        float2 xy0 = *(const float2*)&tile[r0 * 64 + cbase + clo];
        float2 xy1 = *(const float2*)&tile[(r0 + 1) * 64 + cbase + clo];
        o0[i >> 1] = pk(xy0.x, xy1.x);
        o1[i >> 1] = pk(xy0.y, xy1.y);
    }
    *(uint4*)(d + (size_t)col * dld + 8 * a) = *(uint4*)o0;
    *(uint4*)(d + (size_t)(col + 1) * dld + 8 * a) = *(uint4*)o1;
}

// ---------------- prep: W1 (z<8), W2 (z 8..15) transpose + router (z==16) ----

__global__ __launch_bounds__(256) void k_prep(
        const float* __restrict__ W1, const float* __restrict__ W2,
        unsigned short* __restrict__ W1T, unsigned short* __restrict__ W2T,
        const float* __restrict__ x, const float* __restrict__ Wr,
        const float* __restrict__ br, unsigned short* __restrict__ xb,
        int* __restrict__ topk_idx, float* __restrict__ topk_p)
{
    __shared__ float tile[64 * 64];
    int z = blockIdx.z;
    int tid = threadIdx.x;

    if (z == 16) {
        int wv = tid >> 6, lane = tid & 63;
        int t = blockIdx.x * 4 + wv;
        const float* xr = x + (size_t)t * DM;
        unsigned short* xbr = xb + (size_t)t * DM;
        float a0=0,a1=0,a2=0,a3=0,a4=0,a5=0,a6=0,a7=0;
#pragma unroll
        for (int p = 0; p < 4; p++) {
            int d0 = p * 256 + lane * 4;
            float4 xv = *(const float4*)(xr + d0);
            uint2 pkd; pkd.x = pk(xv.x, xv.y); pkd.y = pk(xv.z, xv.w);
            *(uint2*)(xbr + d0) = pkd;
            float xs[4] = {xv.x, xv.y, xv.z, xv.w};
#pragma unroll
            for (int j = 0; j < 4; j++) {
                const float4* wp = (const float4*)(Wr + (d0 + j) * 8);
                float4 w0 = wp[0], w1 = wp[1];
                a0 += xs[j] * w0.x; a1 += xs[j] * w0.y; a2 += xs[j] * w0.z; a3 += xs[j] * w0.w;
                a4 += xs[j] * w1.x; a5 += xs[j] * w1.y; a6 += xs[j] * w1.z; a7 += xs[j] * w1.w;
            }
        }
#pragma unroll
        for (int off = 32; off; off >>= 1) {
            a0 += __shfl_xor(a0, off); a1 += __shfl_xor(a1, off);
            a2 += __shfl_xor(a2, off); a3 += __shfl_xor(a3, off);
            a4 += __shfl_xor(a4, off); a5 += __shfl_xor(a5, off);
            a6 += __shfl_xor(a6, off); a7 += __shfl_xor(a7, off);
        }
        if (lane == 0) {
            float l[8] = {a0 + br[0], a1 + br[1], a2 + br[2], a3 + br[3],
                          a4 + br[4], a5 + br[5], a6 + br[6], a7 + br[7]};
            int i0 = 0;
#pragma unroll
            for (int e = 1; e < 8; e++) if (l[e] > l[i0]) i0 = e;
            int i1 = (i0 == 0) ? 1 : 0;
#pragma unroll
            for (int e = 0; e < 8; e++) if (e != i0 && l[e] > l[i1]) i1 = e;
            float p1 = expf(l[i1] - l[i0]);
            float s = 1.0f + p1;
            topk_idx[2 * t]     = i0;
            topk_idx[2 * t + 1] = i1;
            topk_p[2 * t]       = 1.0f / s;
            topk_p[2 * t + 1]   = p1 / s;
        }
        return;
    }

    if (z < 8) {
        // W1 [D][F] -> W1T [F][D], expert z; blockIdx.x = 64(bx over F) x 16(by over D)
        int bx = blockIdx.x & 63, by = blockIdx.x >> 6;
        transpose64(W1 + (size_t)z * DM * FF + (size_t)(by * 64) * FF + bx * 64, FF,
                    W1T + (size_t)z * DM * FF + (size_t)(bx * 64) * DM + by * 64, DM,
                    tile);
    } else {
        // W2 [F][D] -> W2T [D][F], expert z-8; blockIdx.x = 16(bx over D) x 64(by over F)
        int e = z - 8;
        int bx = blockIdx.x & 15, by = blockIdx.x >> 4;
        transpose64(W2 + (size_t)e * FF * DM + (size_t)(by * 64) * DM + bx * 64, DM,
                    W2T + (size_t)e * DM * FF + (size_t)(bx * 64) * FF + by * 64, FF,
                    tile);
    }
}

// ---------------- route: histogram + prefix + scatter, one block ------------

__global__ __launch_bounds__(256) void k_route2(const int* __restrict__ topk_idx,
        int* __restrict__ cnt, int* __restrict__ offs,
        int* __restrict__ assign_tok, int* __restrict__ assign_e,
        int* __restrict__ slot)
{
    __shared__ int h[8], base[8];
    int tid = threadIdx.x;
    if (tid < 8) h[tid] = 0;
    __syncthreads();
    int el[32];
#pragma unroll
    for (int i = 0; i < 32; i++) {
        int idx = tid * 32 + i;
        el[i] = topk_idx[idx];
        atomicAdd(&h[el[i]], 1);
    }
    __syncthreads();
    if (tid == 0) {
        int s = 0;
        for (int e = 0; e < E_N; e++) { offs[e] = s; cnt[e] = h[e]; base[e] = s; s += h[e]; }
        offs[E_N] = s;
    }
    __syncthreads();
    if (tid < 8) h[tid] = base[tid];
    __syncthreads();
#pragma unroll
    for (int i = 0; i < 32; i++) {
        int idx = tid * 32 + i;
        int e = el[i];
        int pos = atomicAdd(&h[e], 1);
        assign_tok[pos] = idx >> 1;
        assign_e[pos] = e;
        slot[idx] = pos;
    }
}

// ---------------- grouped GEMM, 256x256, 8 waves, 8-phase BK=32 ring --------
// C[off_e+m][n] (+ks*slicePitch) = epi(sum_k A[row(m)][k] * BT[e][n][k]).
// Expert->XCD pinning (e = bid&7), 32 blocks/XCD (1/CU). LDS = 4-slot ring of
// K=32 tiles (A[256][32] | B[256][32] bf16 each, 32KB). Swizzle: 16B slot
// s at row r holds logical k-slot s ^ ((r>>1)&3); staged linearly by
// global_load_lds with inverse-swizzled global source column.
// Phase p (tj=p>>1, mh=p&1): ds_read subtile from ring[tj]; issue 2 gloads of
// tile 4it+3+tj into ring[(tj+3)&3] (freed at phase p-1); s_barrier;
// lgkmcnt(0); 16 MFMA (setprio 1); odd phases: vmcnt(8) BEFORE the closing
// barrier (the barrier publishes completion to all waves); s_barrier.
// Tail keeps vmcnt arithmetic uniform via clamped dummy stages; one full
// drain per output tile only.

template<bool GATHER, bool EPI>
__global__ __launch_bounds__(512, 2) void k_gemm8p(
    const unsigned short* __restrict__ A,
    const unsigned short* __restrict__ BT,
    const float* __restrict__ bias,
    unsigned short* __restrict__ C,
    const int* __restrict__ cnt, const int* __restrict__ offs,
    const int* __restrict__ gather_tok,
    int Kslice, int N, int ldA, int ldB, int GX, int KS, size_t slicePitch)
{
    __shared__ __align__(1024) char lds[4][32768];   // ring: A 16KB | B 16KB

    int bid = blockIdx.x;
    int e = bid & 7;
    int lb = bid >> 3;
    int M = cnt[e];
    if (M <= 0) return;
    int off_e = offs[e];
    int nrows = (M + 255) >> 8;
    int ntiles = nrows * GX * KS;

    int tid = threadIdx.x;
    int wv = tid >> 6, lane = tid & 63;
    int lr = lane & 15, hi = lane >> 4;
    int wr = wv >> 2, wc = wv & 3;
    int ntk = Kslice >> 5;                      // K-tiles of 32
    int sr = lane >> 2;                         // staging row within 16-row unit
    int scol = ((lane & 3) ^ ((lane >> 3) & 3)) * 8;   // inv-swizzled k offset
    int rsw = (lr >> 1) & 3;                    // read-side XOR bits

    for (int t = lb; t < ntiles; t += 32) {
        int r = t % nrows;
        int q = t / nrows;
        int xn = q % GX;
        int ks = q / GX;
        int m0 = r * 256, n0 = xn * 256, kbase = ks * Kslice;

        const unsigned short* aSrc[2];
        const unsigned short* bSrc[2];
#pragma unroll
        for (int i = 0; i < 2; i++) {
            int u = wv * 2 + i;
            int rr = m0 + u * 16 + sr; rr = (rr < M) ? rr : (M - 1);
            size_t arow = GATHER ? (size_t)gather_tok[off_e + rr] : (size_t)(off_e + rr);
            aSrc[i] = A + arow * (size_t)ldA + kbase + scol;
            int nb = n0 + u * 16 + sr;
            bSrc[i] = BT + ((size_t)e * N + nb) * (size_t)ldB + kbase + scol;
        }

        f32x4 acc[8][4];
        f32x4 zz = {0.f, 0.f, 0.f, 0.f};
#pragma unroll
        for (int mi = 0; mi < 8; mi++)
#pragma unroll
            for (int ni = 0; ni < 4; ni++) acc[mi][ni] = zz;

        // prologue: stage K-tiles 0..3 into ring slots 0..3
#pragma unroll
        for (int tt = 0; tt < 4; tt++) {
#pragma unroll
            for (int i = 0; i < 2; i++) {
                gload16(aSrc[i] + tt * 32, lds[tt] + (wv * 2 + i) * 1024);
                gload16(bSrc[i] + tt * 32, lds[tt] + 16384 + (wv * 2 + i) * 1024);
            }
        }
        asm volatile("s_waitcnt vmcnt(12)" ::: "memory");   // tile 0 resident
        __builtin_amdgcn_s_barrier();

        int niter = ntk >> 2;
        for (int it = 0; it < niter; ++it) {
            int k4 = it << 2;
            short8 bfr[4];
#pragma unroll
            for (int p = 0; p < 8; p++) {
                const int tj = p >> 1, mh = p & 1, sb = (tj + 3) & 3;
                const char* cur = lds[tj];
                short8 afr[4];
                if (mh == 0) {
#pragma unroll
                    for (int ni = 0; ni < 4; ni++) {
                        int row = wc * 64 + ni * 16 + lr;
                        bfr[ni] = *(const short8*)(cur + 16384 + row * 64 + ((hi ^ rsw) << 4));
                    }
                }
#pragma unroll
                for (int mi = 0; mi < 4; mi++) {
                    int row = wr * 128 + (mh * 4 + mi) * 16 + lr;
                    afr[mi] = *(const short8*)(cur + row * 64 + ((hi ^ rsw) << 4));
                }
                int st = k4 + 3 + tj;
                if (st >= 4) {                   // skip only iter0 phases 0,1
                    int kof = ((st < ntk) ? st : (ntk - 1)) * 32;  // clamp: dummy at tail
                    gload16(aSrc[mh] + kof, lds[sb] + (wv * 2 + mh) * 1024);
                    gload16(bSrc[mh] + kof, lds[sb] + 16384 + (wv * 2 + mh) * 1024);
                }
                __builtin_amdgcn_s_barrier();
                asm volatile("s_waitcnt lgkmcnt(0)" ::: "memory");
                __builtin_amdgcn_sched_barrier(0);
                __builtin_amdgcn_s_setprio(1);
#pragma unroll
                for (int mi = 0; mi < 4; mi++)
#pragma unroll
                    for (int ni = 0; ni < 4; ni++)
                        acc[mh * 4 + mi][ni] = __builtin_amdgcn_mfma_f32_16x16x32_bf16(
                            afr[mi], bfr[ni], acc[mh * 4 + mi][ni], 0, 0, 0);
                __builtin_amdgcn_s_setprio(0);
                if (mh == 1)
                    asm volatile("s_waitcnt vmcnt(8)" ::: "memory");  // next tile resident
                __builtin_amdgcn_s_barrier();
            }
        }
        asm volatile("s_waitcnt vmcnt(0) lgkmcnt(0)" ::: "memory");  // drain dummies
        __builtin_amdgcn_s_barrier();

        // epilogue
        unsigned short* Cs = C + ks * slicePitch;
        float bv[4] = {0.f, 0.f, 0.f, 0.f};
        if (EPI) {
#pragma unroll
            for (int ni = 0; ni < 4; ni++)
                bv[ni] = bias[(size_t)e * N + (n0 + wc * 64 + ni * 16 + lr)];
        }
#pragma unroll
        for (int mi = 0; mi < 8; mi++) {
            int mb = m0 + wr * 128 + mi * 16 + hi * 4;
#pragma unroll
            for (int rr = 0; rr < 4; rr++) {
                int m = mb + rr;
                if (m < M) {
                    unsigned short* crow = Cs + (size_t)(off_e + m) * N;
#pragma unroll
                    for (int ni = 0; ni < 4; ni++) {
                        float v = acc[mi][ni][rr];
                        if (EPI) v = fmaxf(v + bv[ni], 0.0f);
                        crow[n0 + wc * 64 + ni * 16 + lr] = f2bf(v);
                    }
                }
            }
        }
    }
}

// ---------------- LN1 over F, in-place ----------------

__global__ __launch_bounds__(256) void k_ln1(unsigned short* __restrict__ H,
        const float* __restrict__ g, const float* __restrict__ b,
        const int* __restrict__ assign_e)
{
    size_t a = blockIdx.x;
    int e = assign_e[a];
    unsigned short* row = H + a * FF;
    int tid = threadIdx.x;
    uint4 u0 = *(const uint4*)(row + tid * 16);
    uint4 u1 = *(const uint4*)(row + tid * 16 + 8);
    float v[16];
    unp(u0.x, v[0], v[1]);  unp(u0.y, v[2], v[3]);
    unp(u0.z, v[4], v[5]);  unp(u0.w, v[6], v[7]);
    unp(u1.x, v[8], v[9]);  unp(u1.y, v[10], v[11]);
    unp(u1.z, v[12], v[13]); unp(u1.w, v[14], v[15]);
    float s = 0.f, q = 0.f;
#pragma unroll
    for (int i = 0; i < 16; i++) { s += v[i]; q += v[i] * v[i]; }
#pragma unroll
    for (int off = 32; off; off >>= 1) { s += __shfl_xor(s, off); q += __shfl_xor(q, off); }
    __shared__ float red[8];
    int wv = tid >> 6, lane = tid & 63;
    if (lane == 0) { red[wv * 2] = s; red[wv * 2 + 1] = q; }
    __syncthreads();
    s = red[0] + red[2] + red[4] + red[6];
    q = red[1] + red[3] + red[5] + red[7];
    float mu = s * (1.0f / FF);
    float var = q * (1.0f / FF) - mu * mu;
    float rstd = rsqrtf(var + LN_EPS);
    const float* gg = g + (size_t)e * FF + tid * 16;
    const float* bb = b + (size_t)e * FF + tid * 16;
    float4 G0 = *(const float4*)(gg);      float4 G1 = *(const float4*)(gg + 4);
    float4 G2 = *(const float4*)(gg + 8);  float4 G3 = *(const float4*)(gg + 12);
    float4 B0 = *(const float4*)(bb);      float4 B1 = *(const float4*)(bb + 4);
    float4 B2 = *(const float4*)(bb + 8);  float4 B3 = *(const float4*)(bb + 12);
    float gvv[16] = {G0.x,G0.y,G0.z,G0.w,G1.x,G1.y,G1.z,G1.w,G2.x,G2.y,G2.z,G2.w,G3.x,G3.y,G3.z,G3.w};
    float bvv[16] = {B0.x,B0.y,B0.z,B0.w,B1.x,B1.y,B1.z,B1.w,B2.x,B2.y,B2.z,B2.w,B3.x,B3.y,B3.z,B3.w};
#pragma unroll
    for (int i = 0; i < 16; i++) v[i] = (v[i] - mu) * rstd * gvv[i] + bvv[i];
    u0.x = pk(v[0], v[1]);  u0.y = pk(v[2], v[3]);
    u0.z = pk(v[4], v[5]);  u0.w = pk(v[6], v[7]);
    u1.x = pk(v[8], v[9]);  u1.y = pk(v[10], v[11]);
    u1.z = pk(v[12], v[13]); u1.w = pk(v[14], v[15]);
    *(uint4*)(row + tid * 16) = u0;
    *(uint4*)(row + tid * 16 + 8) = u1;
}

// ---------------- combine: sum split-K partials + bias + relu + LN2 + gate --

__global__ __launch_bounds__(256) void k_comb(const unsigned short* __restrict__ Yp,
        const float* __restrict__ g, const float* __restrict__ b2,
        const float* __restrict__ be,
        const int* __restrict__ slot, const float* __restrict__ topk_p,
        const int* __restrict__ assign_e, float* __restrict__ out)
{
    int t = blockIdx.x;
    int s0 = slot[2 * t], s1 = slot[2 * t + 1];
    float p0 = topk_p[2 * t], p1 = topk_p[2 * t + 1];
    int e0 = assign_e[s0], e1 = assign_e[s1];
    int tid = threadIdx.x;
    int d = tid * 4;
    const unsigned short* Y1 = Yp + (size_t)NA * DM;
    uint2 ua0 = *(const uint2*)(Yp + (size_t)s0 * DM + d);
    uint2 ua1 = *(const uint2*)(Y1 + (size_t)s0 * DM + d);
    uint2 ub0 = *(const uint2*)(Yp + (size_t)s1 * DM + d);
    uint2 ub1 = *(const uint2*)(Y1 + (size_t)s1 * DM + d);
    float4 bza = *(const float4*)(b2 + (size_t)e0 * DM + d);
    float4 bzb = *(const float4*)(b2 + (size_t)e1 * DM + d);
    float x0, x1, y0, y1;
    float va[4], vb[4];
    unp(ua0.x, x0, x1); unp(ua1.x, y0, y1);
    va[0] = fmaxf(x0 + y0 + bza.x, 0.f); va[1] = fmaxf(x1 + y1 + bza.y, 0.f);
    unp(ua0.y, x0, x1); unp(ua1.y, y0, y1);
    va[2] = fmaxf(x0 + y0 + bza.z, 0.f); va[3] = fmaxf(x1 + y1 + bza.w, 0.f);
    unp(ub0.x, x0, x1); unp(ub1.x, y0, y1);
    vb[0] = fmaxf(x0 + y0 + bzb.x, 0.f); vb[1] = fmaxf(x1 + y1 + bzb.y, 0.f);
    unp(ub0.y, x0, x1); unp(ub1.y, y0, y1);
    vb[2] = fmaxf(x0 + y0 + bzb.z, 0.f); vb[3] = fmaxf(x1 + y1 + bzb.w, 0.f);

    float sa = 0.f, qa = 0.f, sb = 0.f, qb = 0.f;
#pragma unroll
    for (int i = 0; i < 4; i++) {
        sa += va[i]; qa += va[i] * va[i];
        sb += vb[i]; qb += vb[i] * vb[i];
    }
#pragma unroll
    for (int off = 32; off; off >>= 1) {
        sa += __shfl_xor(sa, off); qa += __shfl_xor(qa, off);
        sb += __shfl_xor(sb, off); qb += __shfl_xor(qb, off);
    }
    __shared__ float red[16];
    int wv = tid >> 6, lane = tid & 63;
    if (lane == 0) { red[wv*4+0]=sa; red[wv*4+1]=qa; red[wv*4+2]=sb; red[wv*4+3]=qb; }
    __syncthreads();
    sa = red[0] + red[4] + red[8]  + red[12];
    qa = red[1] + red[5] + red[9]  + red[13];
    sb = red[2] + red[6] + red[10] + red[14];
    qb = red[3] + red[7] + red[11] + red[15];
    float mua = sa * (1.0f / DM), vara = qa * (1.0f / DM) - mua * mua;
    float ra = rsqrtf(vara + LN_EPS);
    float mub = sb * (1.0f / DM), varb = qb * (1.0f / DM) - mub * mub;
    float rb = rsqrtf(varb + LN_EPS);
    float4 ga  = *(const float4*)(g + (size_t)e0 * DM + d);
    float4 ba  = *(const float4*)(be + (size_t)e0 * DM + d);
    float4 gb4 = *(const float4*)(g + (size_t)e1 * DM + d);
    float4 bb4 = *(const float4*)(be + (size_t)e1 * DM + d);
    float4 o;
    o.x = p0 * ((va[0] - mua) * ra * ga.x + ba.x) + p1 * ((vb[0] - mub) * rb * gb4.x + bb4.x);
    o.y = p0 * ((va[1] - mua) * ra * ga.y + ba.y) + p1 * ((vb[1] - mub) * rb * gb4.y + bb4.y);
    o.z = p0 * ((va[2] - mua) * ra * ga.z + ba.z) + p1 * ((vb[2] - mub) * rb * gb4.z + bb4.z);
    o.w = p0 * ((va[3] - mua) * ra * ga.w + ba.w) + p1 * ((vb[3] - mub) * rb * gb4.w + bb4.w);
    *(float4*)(out + (size_t)t * DM + d) = o;
}

// ---------------- launch ----------------

extern "C" void kernel_launch(void* const* d_in, const int* in_sizes, int n_in,
                              void* d_out, int out_size, void* d_ws, size_t ws_size,
                              hipStream_t stream) {
    const float* x   = (const float*)d_in[0];
    const float* Wr  = (const float*)d_in[1];
    const float* br  = (const float*)d_in[2];
    const float* W1  = (const float*)d_in[3];
    const float* b1  = (const float*)d_in[4];
    const float* g1  = (const float*)d_in[5];
    const float* be1 = (const float*)d_in[6];
    const float* W2  = (const float*)d_in[7];
    const float* b2  = (const float*)d_in[8];
    const float* g2  = (const float*)d_in[9];
    const float* be2 = (const float*)d_in[10];
    float* out = (float*)d_out;

    char* w = (char*)d_ws;
    int*   cnt        = (int*)(w);
    int*   offs       = (int*)(w + 128);
    int*   topk_idx   = (int*)(w + 512);
    float* topk_p     = (float*)(w + 512 + (32 << 10));
    int*   assign_tok = (int*)(w + 512 + (64 << 10));
    int*   assign_e   = (int*)(w + 512 + (96 << 10));
    int*   slot       = (int*)(w + 512 + (128 << 10));
    unsigned short* xb  = (unsigned short*)(w + ((size_t)1 << 20));
    unsigned short* W1T = (unsigned short*)(w + ((size_t)9 << 20));    // [E][F][D] bf16
    unsigned short* W2T = (unsigned short*)(w + ((size_t)73 << 20));   // [E][D][F] bf16
    unsigned short* Hb  = (unsigned short*)(w + ((size_t)137 << 20));  // [NA][F] bf16
    unsigned short* Yp  = (unsigned short*)(w + ((size_t)201 << 20));  // [2][NA][D] bf16

    // prep: z 0..7 W1 transpose, 8..15 W2 transpose, 16 router (+x->bf16)
    k_prep<<<dim3(1024, 1, 17), 256, 0, stream>>>(
        W1, W2, W1T, W2T, x, Wr, br, xb, topk_idx, topk_p);
    k_route2<<<1, 256, 0, stream>>>(topk_idx, cnt, offs, assign_tok, assign_e, slot);
    // GEMM1: gathered x rows x W1T -> Hb(+bias,relu); K=1024, GX=16, KS=1
    k_gemm8p<true, true><<<256, 512, 0, stream>>>(
        xb, W1T, b1, Hb, cnt, offs, assign_tok, DM, FF, DM, DM, 16, 1, 0);
    k_ln1<<<NA, 256, 0, stream>>>(Hb, g1, be1, assign_e);
    // GEMM2: Hb x W2T -> Yp partials; Kslice=2048, KS=2, GX=4
    k_gemm8p<false, false><<<256, 512, 0, stream>>>(
        Hb, W2T, nullptr, Yp, cnt, offs, nullptr, FF / 2, DM, FF, FF, 4, 2,
        (size_t)NA * DM);
    k_comb<<<NTOK, 256, 0, stream>>>(Yp, g2, b2, be2, slot, topk_p, assign_e, out);
}

// Round 10
// 343.637 us; speedup vs baseline: 1.0312x; 1.0312x over previous
//
#include <hip/hip_runtime.h>

// Mixture-of-Experts, sparse top-2.
// Round 10: r7 structure (persistent 2-barrier 128^2 grouped GEMM, expert->XCD
// pinning, split-K GEMM2) + snake block-decode in the transpose prep (read AND
// write DRAM adjacency across concurrent blocks) + vectorized router.

#define E_N 8
#define TOPK 2
#define DM 1024
#define FF 4096
#define NTOK 4096
#define NA 8192
#define LN_EPS 1e-5f
#define NBX 128   // persistent blocks per XCD (1024 total / 8)

typedef __attribute__((ext_vector_type(4))) float f32x4;
typedef __attribute__((ext_vector_type(8))) short short8;

__device__ __forceinline__ unsigned short f2bf(float f) {
    unsigned int u = __builtin_bit_cast(unsigned int, f);
    u = (u + 0x7FFFu + ((u >> 16) & 1u)) >> 16;   // RNE
    return (unsigned short)u;
}
__device__ __forceinline__ float bf2f(unsigned short h) {
    unsigned int u = ((unsigned int)h) << 16;
    return __builtin_bit_cast(float, u);
}
__device__ __forceinline__ void unp(unsigned int u, float& lo, float& hi) {
    lo = bf2f((unsigned short)(u & 0xffffu));
    hi = bf2f((unsigned short)(u >> 16));
}
__device__ __forceinline__ unsigned int pk(float lo, float hi) {
    return (unsigned int)f2bf(lo) | ((unsigned int)f2bf(hi) << 16);
}

__device__ __forceinline__ void gload16(const unsigned short* g, unsigned short* lds) {
    __builtin_amdgcn_global_load_lds(
        (const __attribute__((address_space(1))) unsigned int*)g,
        (__attribute__((address_space(3))) unsigned int*)lds, 16, 0, 0);
}

// ---------------- prep: W1/W2 transpose (z<16, snake decode) + router (z==16)

__global__ __launch_bounds__(256) void k_prep(
        const float* __restrict__ W1, const float* __restrict__ W2,
        unsigned short* __restrict__ W1T, unsigned short* __restrict__ W2T,
        const float* __restrict__ x, const float* __restrict__ Wr,
        const float* __restrict__ br, unsigned short* __restrict__ xb,
        int* __restrict__ topk_idx, float* __restrict__ topk_p)
{
    __shared__ float tile[64][65];
    int z = blockIdx.z;
    int tid = threadIdx.x;

    if (z == 16) {
        // router, 4 tokens/block, fused x->bf16 (vectorized)
        int wv = tid >> 6, lane = tid & 63;
        int t = blockIdx.x * 4 + wv;
        const float* xr = x + (size_t)t * DM;
        unsigned short* xbr = xb + (size_t)t * DM;
        float a0=0,a1=0,a2=0,a3=0,a4=0,a5=0,a6=0,a7=0;
#pragma unroll
        for (int p = 0; p < 4; p++) {
            int d0 = p * 256 + lane * 4;
            float4 xv = *(const float4*)(xr + d0);
            uint2 pkd; pkd.x = pk(xv.x, xv.y); pkd.y = pk(xv.z, xv.w);
            *(uint2*)(xbr + d0) = pkd;
            float xs[4] = {xv.x, xv.y, xv.z, xv.w};
#pragma unroll
            for (int j = 0; j < 4; j++) {
                const float4* wp = (const float4*)(Wr + (d0 + j) * 8);
                float4 w0 = wp[0], w1 = wp[1];
                a0 += xs[j] * w0.x; a1 += xs[j] * w0.y; a2 += xs[j] * w0.z; a3 += xs[j] * w0.w;
                a4 += xs[j] * w1.x; a5 += xs[j] * w1.y; a6 += xs[j] * w1.z; a7 += xs[j] * w1.w;
            }
        }
#pragma unroll
        for (int off = 32; off; off >>= 1) {
            a0 += __shfl_xor(a0, off); a1 += __shfl_xor(a1, off);
            a2 += __shfl_xor(a2, off); a3 += __shfl_xor(a3, off);
            a4 += __shfl_xor(a4, off); a5 += __shfl_xor(a5, off);
            a6 += __shfl_xor(a6, off); a7 += __shfl_xor(a7, off);
        }
        if (lane == 0) {
            float l[8] = {a0 + br[0], a1 + br[1], a2 + br[2], a3 + br[3],
                          a4 + br[4], a5 + br[5], a6 + br[6], a7 + br[7]};
            int i0 = 0;
#pragma unroll
            for (int e = 1; e < 8; e++) if (l[e] > l[i0]) i0 = e;
            int i1 = (i0 == 0) ? 1 : 0;
#pragma unroll
            for (int e = 0; e < 8; e++) if (e != i0 && l[e] > l[i1]) i1 = e;
            float p1 = expf(l[i1] - l[i0]);
            float s = 1.0f + p1;
            topk_idx[2 * t]     = i0;
            topk_idx[2 * t + 1] = i1;
            topk_p[2 * t]       = 1.0f / s;
            topk_p[2 * t + 1]   = p1 / s;
        }
        return;
    }

    // transpose [R][C] f32 -> [C][R] bf16, 64x64 tiles.
    // Snake decode: concurrent blocks form 4(bx) x 16(by) supertiles so reads
    // are 1KB-adjacent per input row AND writes are 2KB-contiguous per out-row.
    int id = blockIdx.x;
    int bxl = id & 3, byl = (id >> 2) & 15, gg = id >> 6;
    const float* src; unsigned short* dst; int R, C, bx, by;
    if (z < 8) {
        R = DM; C = FF;                       // grid 64(bx) x 16(by)
        src = W1 + (size_t)z * R * C;  dst = W1T + (size_t)z * R * C;
        bx = gg * 4 + bxl;  by = byl;
    } else {
        R = FF; C = DM;                       // grid 16(bx) x 64(by)
        src = W2 + (size_t)(z - 8) * R * C;  dst = W2T + (size_t)(z - 8) * R * C;
        bx = (gg & 3) * 4 + bxl;  by = (gg >> 2) * 16 + byl;
    }
    const float* s = src + (size_t)(by * 64) * C + bx * 64;
    unsigned short* d = dst + (size_t)(bx * 64) * R + by * 64;
    int lr = tid >> 4, lc = (tid & 15) * 4;
#pragma unroll
    for (int p = 0; p < 4; p++) {
        float4 v = *(const float4*)(s + (size_t)(lr + p * 16) * C + lc);
        tile[lr + p * 16][lc] = v.x;     tile[lr + p * 16][lc + 1] = v.y;
        tile[lr + p * 16][lc + 2] = v.z; tile[lr + p * 16][lc + 3] = v.w;
    }
    __syncthreads();
    int rc = (tid & 7) * 8;
#pragma unroll
    for (int p = 0; p < 2; p++) {
        int cc = (tid >> 3) + p * 32;
        float a0 = tile[rc + 0][cc], a1 = tile[rc + 1][cc];
        float a2 = tile[rc + 2][cc], a3 = tile[rc + 3][cc];
        float a4 = tile[rc + 4][cc], a5 = tile[rc + 5][cc];
        float a6 = tile[rc + 6][cc], a7 = tile[rc + 7][cc];
        uint4 o;
        o.x = pk(a0, a1); o.y = pk(a2, a3); o.z = pk(a4, a5); o.w = pk(a6, a7);
        *(uint4*)(d + (size_t)cc * R + rc) = o;
    }
}

// ---------------- route: histogram + prefix + scatter, one block ------------

__global__ __launch_bounds__(256) void k_route2(const int* __restrict__ topk_idx,
        int* __restrict__ cnt, int* __restrict__ offs,
        int* __restrict__ assign_tok, int* __restrict__ assign_e,
        int* __restrict__ slot)
{
    __shared__ int h[8], base[8];
    int tid = threadIdx.x;
    if (tid < 8) h[tid] = 0;
    __syncthreads();
    int el[32];
#pragma unroll
    for (int i = 0; i < 32; i++) {
        int idx = tid * 32 + i;
        el[i] = topk_idx[idx];
        atomicAdd(&h[el[i]], 1);
    }
    __syncthreads();
    if (tid == 0) {
        int s = 0;
        for (int e = 0; e < E_N; e++) { offs[e] = s; cnt[e] = h[e]; base[e] = s; s += h[e]; }
        offs[E_N] = s;
    }
    __syncthreads();
    if (tid < 8) h[tid] = base[tid];
    __syncthreads();
#pragma unroll
    for (int i = 0; i < 32; i++) {
        int idx = tid * 32 + i;
        int e = el[i];
        int pos = atomicAdd(&h[e], 1);
        assign_tok[pos] = idx >> 1;
        assign_e[pos] = e;
        slot[idx] = pos;
    }
}

// ---------------- persistent grouped GEMM, 128x128, 4 waves, m97 K-loop -----
// Block bid pinned to expert e = bid&7 (== its XCD). lb = bid>>3 in [0,128)
// strides the expert's tile list t = ((ks*GX)+xn)*nrows + r (y fastest ->
// consecutive blocks share a B panel in L2). Single 32KB LDS buffer, XOR
// swizzle, global_load_lds(16B), setprio around MFMA.

template<bool GATHER, bool EPI>
__global__ __launch_bounds__(256, 4) void k_gemm(
    const unsigned short* __restrict__ A,
    const unsigned short* __restrict__ BT,
    const float* __restrict__ bias,
    unsigned short* __restrict__ C,
    const int* __restrict__ cnt, const int* __restrict__ offs,
    const int* __restrict__ gather_tok,
    int Kslice, int N, int ldA, int ldB, int GX, int KS, size_t slicePitch)
{
    __shared__ __align__(1024) char lds[32768];   // A 16KB | B 16KB

    int bid = blockIdx.x;
    int e = bid & 7;                 // expert == XCD
    int lb = bid >> 3;
    int M = cnt[e];
    if (M <= 0) return;
    int off_e = offs[e];
    int nrows = (M + 127) >> 7;
    int ntiles = nrows * GX * KS;

    int tid = threadIdx.x;
    int wv = tid >> 6, lane = tid & 63;
    int lr = lane & 15, hi = lane >> 4;
    int mW = (wv >> 1) * 64, nW = (wv & 1) * 64;
    int colsw = ((lane & 7) ^ (lane >> 3)) * 8;
    int l3 = lane >> 3;
    int nt = Kslice >> 6;

    for (int t = lb; t < ntiles; t += NBX) {
        int r = t % nrows;
        int q = t / nrows;
        int xn = q % GX;
        int ks = q / GX;
        int m0 = r * 128;
        int n0 = xn * 128;
        int kbase = ks * Kslice;

        const unsigned short* aptr[4];
        const unsigned short* bptr[4];
#pragma unroll
        for (int i = 0; i < 4; i++) {
            int j = wv * 4 + i;
            int rr = m0 + j * 8 + l3; rr = (rr < M) ? rr : (M - 1);
            size_t arow = GATHER ? (size_t)gather_tok[off_e + rr] : (size_t)(off_e + rr);
            aptr[i] = A + arow * (size_t)ldA + kbase + colsw;
            int rb = n0 + j * 8 + l3;
            bptr[i] = BT + ((size_t)e * N + rb) * (size_t)ldB + kbase + colsw;
        }

        f32x4 acc[4][4];
        f32x4 zz = {0.f, 0.f, 0.f, 0.f};
#pragma unroll
        for (int mi = 0; mi < 4; mi++)
#pragma unroll
            for (int ni = 0; ni < 4; ni++) acc[mi][ni] = zz;

        for (int kt = 0; kt < nt; ++kt) {
            __syncthreads();                  // prev tile fully consumed
#pragma unroll
            for (int i = 0; i < 4; i++) {
                gload16(aptr[i] + kt * 64, (unsigned short*)(lds + (wv * 4 + i) * 1024));
                gload16(bptr[i] + kt * 64, (unsigned short*)(lds + 16384 + (wv * 4 + i) * 1024));
            }
            __syncthreads();                  // drains vmcnt before barrier
#pragma unroll
            for (int kss = 0; kss < 2; kss++) {
                int cb = (kss * 64 + hi * 16) ^ ((lr & 7) << 4);
                short8 afr[4], bfr[4];
#pragma unroll
                for (int ni = 0; ni < 4; ni++)
                    bfr[ni] = *(const short8*)(lds + 16384 + (nW + ni * 16 + lr) * 128 + cb);
#pragma unroll
                for (int mi = 0; mi < 4; mi++)
                    afr[mi] = *(const short8*)(lds + (mW + mi * 16 + lr) * 128 + cb);
                __builtin_amdgcn_s_setprio(1);
#pragma unroll
                for (int mi = 0; mi < 4; mi++)
#pragma unroll
                    for (int ni = 0; ni < 4; ni++)
                        acc[mi][ni] = __builtin_amdgcn_mfma_f32_16x16x32_bf16(
                            afr[mi], bfr[ni], acc[mi][ni], 0, 0, 0);
                __builtin_amdgcn_s_setprio(0);
            }
        }

        unsigned short* Cs = C + ks * slicePitch;
        float bv[4] = {0.f, 0.f, 0.f, 0.f};
        if (EPI) {
#pragma unroll
            for (int ni = 0; ni < 4; ni++)
                bv[ni] = bias[(size_t)e * N + (n0 + nW + ni * 16 + lr)];
        }
#pragma unroll
        for (int mi = 0; mi < 4; mi++) {
            int mb = m0 + mW + mi * 16 + hi * 4;
#pragma unroll
            for (int rr = 0; rr < 4; rr++) {
                int m = mb + rr;
                if (m < M) {
                    unsigned short* crow = Cs + (size_t)(off_e + m) * N;
#pragma unroll
                    for (int ni = 0; ni < 4; ni++) {
                        float v = acc[mi][ni][rr];
                        if (EPI) v = fmaxf(v + bv[ni], 0.0f);
                        crow[n0 + nW + ni * 16 + lr] = f2bf(v);
                    }
                }
            }
        }
    }
}

// ---------------- LN1 over F, in-place ----------------

__global__ __launch_bounds__(256) void k_ln1(unsigned short* __restrict__ H,
        const float* __restrict__ g, const float* __restrict__ b,
        const int* __restrict__ assign_e)
{
    size_t a = blockIdx.x;
    int e = assign_e[a];
    unsigned short* row = H + a * FF;
    int tid = threadIdx.x;
    uint4 u0 = *(const uint4*)(row + tid * 16);
    uint4 u1 = *(const uint4*)(row + tid * 16 + 8);
    float v[16];
    unp(u0.x, v[0], v[1]);  unp(u0.y, v[2], v[3]);
    unp(u0.z, v[4], v[5]);  unp(u0.w, v[6], v[7]);
    unp(u1.x, v[8], v[9]);  unp(u1.y, v[10], v[11]);
    unp(u1.z, v[12], v[13]); unp(u1.w, v[14], v[15]);
    float s = 0.f, q = 0.f;
#pragma unroll
    for (int i = 0; i < 16; i++) { s += v[i]; q += v[i] * v[i]; }
#pragma unroll
    for (int off = 32; off; off >>= 1) { s += __shfl_xor(s, off); q += __shfl_xor(q, off); }
    __shared__ float red[8];
    int wv = tid >> 6, lane = tid & 63;
    if (lane == 0) { red[wv * 2] = s; red[wv * 2 + 1] = q; }
    __syncthreads();
    s = red[0] + red[2] + red[4] + red[6];
    q = red[1] + red[3] + red[5] + red[7];
    float mu = s * (1.0f / FF);
    float var = q * (1.0f / FF) - mu * mu;
    float rstd = rsqrtf(var + LN_EPS);
    const float* gg = g + (size_t)e * FF + tid * 16;
    const float* bb = b + (size_t)e * FF + tid * 16;
    float4 G0 = *(const float4*)(gg);      float4 G1 = *(const float4*)(gg + 4);
    float4 G2 = *(const float4*)(gg + 8);  float4 G3 = *(const float4*)(gg + 12);
    float4 B0 = *(const float4*)(bb);      float4 B1 = *(const float4*)(bb + 4);
    float4 B2 = *(const float4*)(bb + 8);  float4 B3 = *(const float4*)(bb + 12);
    float gvv[16] = {G0.x,G0.y,G0.z,G0.w,G1.x,G1.y,G1.z,G1.w,G2.x,G2.y,G2.z,G2.w,G3.x,G3.y,G3.z,G3.w};
    float bvv[16] = {B0.x,B0.y,B0.z,B0.w,B1.x,B1.y,B1.z,B1.w,B2.x,B2.y,B2.z,B2.w,B3.x,B3.y,B3.z,B3.w};
#pragma unroll
    for (int i = 0; i < 16; i++) v[i] = (v[i] - mu) * rstd * gvv[i] + bvv[i];
    u0.x = pk(v[0], v[1]);  u0.y = pk(v[2], v[3]);
    u0.z = pk(v[4], v[5]);  u0.w = pk(v[6], v[7]);
    u1.x = pk(v[8], v[9]);  u1.y = pk(v[10], v[11]);
    u1.z = pk(v[12], v[13]); u1.w = pk(v[14], v[15]);
    *(uint4*)(row + tid * 16) = u0;
    *(uint4*)(row + tid * 16 + 8) = u1;
}

// ---------------- combine: sum split-K partials + bias + relu + LN2 + gate --

__global__ __launch_bounds__(256) void k_comb(const unsigned short* __restrict__ Yp,
        const float* __restrict__ g, const float* __restrict__ b2,
        const float* __restrict__ be,
        const int* __restrict__ slot, const float* __restrict__ topk_p,
        const int* __restrict__ assign_e, float* __restrict__ out)
{
    int t = blockIdx.x;
    int s0 = slot[2 * t], s1 = slot[2 * t + 1];
    float p0 = topk_p[2 * t], p1 = topk_p[2 * t + 1];
    int e0 = assign_e[s0], e1 = assign_e[s1];
    int tid = threadIdx.x;
    int d = tid * 4;
    const unsigned short* Y1 = Yp + (size_t)NA * DM;
    uint2 ua0 = *(const uint2*)(Yp + (size_t)s0 * DM + d);
    uint2 ua1 = *(const uint2*)(Y1 + (size_t)s0 * DM + d);
    uint2 ub0 = *(const uint2*)(Yp + (size_t)s1 * DM + d);
    uint2 ub1 = *(const uint2*)(Y1 + (size_t)s1 * DM + d);
    float4 bza = *(const float4*)(b2 + (size_t)e0 * DM + d);
    float4 bzb = *(const float4*)(b2 + (size_t)e1 * DM + d);
    float x0, x1, y0, y1;
    float va[4], vb[4];
    unp(ua0.x, x0, x1); unp(ua1.x, y0, y1);
    va[0] = fmaxf(x0 + y0 + bza.x, 0.f); va[1] = fmaxf(x1 + y1 + bza.y, 0.f);
    unp(ua0.y, x0, x1); unp(ua1.y, y0, y1);
    va[2] = fmaxf(x0 + y0 + bza.z, 0.f); va[3] = fmaxf(x1 + y1 + bza.w, 0.f);
    unp(ub0.x, x0, x1); unp(ub1.x, y0, y1);
    vb[0] = fmaxf(x0 + y0 + bzb.x, 0.f); vb[1] = fmaxf(x1 + y1 + bzb.y, 0.f);
    unp(ub0.y, x0, x1); unp(ub1.y, y0, y1);
    vb[2] = fmaxf(x0 + y0 + bzb.z, 0.f); vb[3] = fmaxf(x1 + y1 + bzb.w, 0.f);

    float sa = 0.f, qa = 0.f, sb = 0.f, qb = 0.f;
#pragma unroll
    for (int i = 0; i < 4; i++) {
        sa += va[i]; qa += va[i] * va[i];
        sb += vb[i]; qb += vb[i] * vb[i];
    }
#pragma unroll
    for (int off = 32; off; off >>= 1) {
        sa += __shfl_xor(sa, off); qa += __shfl_xor(qa, off);
        sb += __shfl_xor(sb, off); qb += __shfl_xor(qb, off);
    }
    __shared__ float red[16];
    int wv = tid >> 6, lane = tid & 63;
    if (lane == 0) { red[wv*4+0]=sa; red[wv*4+1]=qa; red[wv*4+2]=sb; red[wv*4+3]=qb; }
    __syncthreads();
    sa = red[0] + red[4] + red[8]  + red[12];
    qa = red[1] + red[5] + red[9]  + red[13];
    sb = red[2] + red[6] + red[10] + red[14];
    qb = red[3] + red[7] + red[11] + red[15];
    float mua = sa * (1.0f / DM), vara = qa * (1.0f / DM) - mua * mua;
    float ra = rsqrtf(vara + LN_EPS);
    float mub = sb * (1.0f / DM), varb = qb * (1.0f / DM) - mub * mub;
    float rb = rsqrtf(varb + LN_EPS);
    float4 ga  = *(const float4*)(g + (size_t)e0 * DM + d);
    float4 ba  = *(const float4*)(be + (size_t)e0 * DM + d);
    float4 gb4 = *(const float4*)(g + (size_t)e1 * DM + d);
    float4 bb4 = *(const float4*)(be + (size_t)e1 * DM + d);
    float4 o;
    o.x = p0 * ((va[0] - mua) * ra * ga.x + ba.x) + p1 * ((vb[0] - mub) * rb * gb4.x + bb4.x);
    o.y = p0 * ((va[1] - mua) * ra * ga.y + ba.y) + p1 * ((vb[1] - mub) * rb * gb4.y + bb4.y);
    o.z = p0 * ((va[2] - mua) * ra * ga.z + ba.z) + p1 * ((vb[2] - mub) * rb * gb4.z + bb4.z);
    o.w = p0 * ((va[3] - mua) * ra * ga.w + ba.w) + p1 * ((vb[3] - mub) * rb * gb4.w + bb4.w);
    *(float4*)(out + (size_t)t * DM + d) = o;
}

// ---------------- launch ----------------

extern "C" void kernel_launch(void* const* d_in, const int* in_sizes, int n_in,
                              void* d_out, int out_size, void* d_ws, size_t ws_size,
                              hipStream_t stream) {
    const float* x   = (const float*)d_in[0];
    const float* Wr  = (const float*)d_in[1];
    const float* br  = (const float*)d_in[2];
    const float* W1  = (const float*)d_in[3];
    const float* b1  = (const float*)d_in[4];
    const float* g1  = (const float*)d_in[5];
    const float* be1 = (const float*)d_in[6];
    const float* W2  = (const float*)d_in[7];
    const float* b2  = (const float*)d_in[8];
    const float* g2  = (const float*)d_in[9];
    const float* be2 = (const float*)d_in[10];
    float* out = (float*)d_out;

    char* w = (char*)d_ws;
    int*   cnt        = (int*)(w);
    int*   offs       = (int*)(w + 128);
    int*   topk_idx   = (int*)(w + 512);
    float* topk_p     = (float*)(w + 512 + (32 << 10));
    int*   assign_tok = (int*)(w + 512 + (64 << 10));
    int*   assign_e   = (int*)(w + 512 + (96 << 10));
    int*   slot       = (int*)(w + 512 + (128 << 10));
    unsigned short* xb  = (unsigned short*)(w + ((size_t)1 << 20));
    unsigned short* W1T = (unsigned short*)(w + ((size_t)9 << 20));    // [E][F][D] bf16
    unsigned short* W2T = (unsigned short*)(w + ((size_t)73 << 20));   // [E][D][F] bf16
    unsigned short* Hb  = (unsigned short*)(w + ((size_t)137 << 20));  // [NA][F] bf16
    unsigned short* Yp  = (unsigned short*)(w + ((size_t)201 << 20));  // [2][NA][D] bf16

    // prep: z 0..7 transpose W1, 8..15 transpose W2 (snake decode), 16 router
    k_prep<<<dim3(1024, 1, 17), 256, 0, stream>>>(
        W1, W2, W1T, W2T, x, Wr, br, xb, topk_idx, topk_p);
    k_route2<<<1, 256, 0, stream>>>(topk_idx, cnt, offs, assign_tok, assign_e, slot);
    // GEMM1: gathered x rows x W1T -> Hb(+bias,relu); K=1024, GX=32, KS=1
    k_gemm<true, true><<<8 * NBX, 256, 0, stream>>>(
        xb, W1T, b1, Hb, cnt, offs, assign_tok, DM, FF, DM, DM, 32, 1, 0);
    k_ln1<<<NA, 256, 0, stream>>>(Hb, g1, be1, assign_e);
    // GEMM2: Hb x W2T -> Yp partials; Kslice=2048, KS=2, GX=8
    k_gemm<false, false><<<8 * NBX, 256, 0, stream>>>(
        Hb, W2T, nullptr, Yp, cnt, offs, nullptr, FF / 2, DM, FF, FF, 8, 2,
        (size_t)NA * DM);
    k_comb<<<NTOK, 256, 0, stream>>>(Yp, g2, b2, be2, slot, topk_p, assign_e, out);
}

// Round 11
// 339.798 us; speedup vs baseline: 1.0428x; 1.0113x over previous
//
#include <hip/hip_runtime.h>

// Mixture-of-Experts, sparse top-2.
// Round 11: r7 structure exactly (persistent 2-barrier 128^2 grouped GEMM,
// expert->XCD pinning, split-K GEMM2, scalar router) with ONE change:
// 128x64 transpose tiles -> 256B-contiguous output-row writes, col-XOR LDS.

#define E_N 8
#define TOPK 2
#define DM 1024
#define FF 4096
#define NTOK 4096
#define NA 8192
#define LN_EPS 1e-5f
#define NBX 128   // persistent blocks per XCD (1024 total / 8)

typedef __attribute__((ext_vector_type(4))) float f32x4;
typedef __attribute__((ext_vector_type(8))) short short8;

__device__ __forceinline__ unsigned short f2bf(float f) {
    unsigned int u = __builtin_bit_cast(unsigned int, f);
    u = (u + 0x7FFFu + ((u >> 16) & 1u)) >> 16;   // RNE
    return (unsigned short)u;
}
__device__ __forceinline__ float bf2f(unsigned short h) {
    unsigned int u = ((unsigned int)h) << 16;
    return __builtin_bit_cast(float, u);
}
__device__ __forceinline__ void unp(unsigned int u, float& lo, float& hi) {
    lo = bf2f((unsigned short)(u & 0xffffu));
    hi = bf2f((unsigned short)(u >> 16));
}
__device__ __forceinline__ unsigned int pk(float lo, float hi) {
    return (unsigned int)f2bf(lo) | ((unsigned int)f2bf(hi) << 16);
}

__device__ __forceinline__ void gload16(const unsigned short* g, unsigned short* lds) {
    __builtin_amdgcn_global_load_lds(
        (const __attribute__((address_space(1))) unsigned int*)g,
        (__attribute__((address_space(3))) unsigned int*)lds, 16, 0, 0);
}

// ---- 128x64 f32 -> bf16 transpose. Input tile [128 r][64 c]; output [64][128].
// LDS [128][64] f32, col-XOR swizzle col' = col ^ ((r>>5)<<3):
//  phase1: coalesced float4 loads (256B/row), swizzled float4 LDS writes.
//  phase2: thread t (o=t>>2, k0=(t&3)*32) reads col (o^((t&3)<<3)) of rows
//          k0..k0+31 (2-way banks, free), packs bf16, writes 64B contiguous;
//          threads 0..3 cover 256B of one output row.
__device__ __forceinline__ void transpose128x64(const float* __restrict__ s, int sld,
                                                unsigned short* __restrict__ d, int dld,
                                                float* tile) {
    int tid = threadIdx.x;
    int rr = tid >> 4, cc = (tid & 15) * 4;
#pragma unroll
    for (int p = 0; p < 8; p++) {
        int r = rr + p * 16;
        float4 v = *(const float4*)(s + (size_t)r * sld + cc);
        *(float4*)&tile[r * 64 + (cc ^ ((r >> 5) << 3))] = v;
    }
    __syncthreads();
    int o = tid >> 2;                 // out-row (= input col) 0..63
    int k0 = (tid & 3) * 32;          // out-col base (= input row)
    int q8 = (tid & 3) << 3;
    const float* base = tile + (size_t)k0 * 64 + (o ^ q8);
    unsigned int ov[16];
#pragma unroll
    for (int m = 0; m < 16; m++) {
        float x0 = base[(2 * m) * 64];
        float x1 = base[(2 * m + 1) * 64];
        ov[m] = pk(x0, x1);
    }
    unsigned short* dp = d + (size_t)o * dld + k0;
    *(uint4*)(dp)      = *(uint4*)&ov[0];
    *(uint4*)(dp + 8)  = *(uint4*)&ov[4];
    *(uint4*)(dp + 16) = *(uint4*)&ov[8];
    *(uint4*)(dp + 24) = *(uint4*)&ov[12];
}

// ---------------- prep: W1 (z<8) / W2 (z 8..15) transpose + router (z==16) --

__global__ __launch_bounds__(256) void k_prep(
        const float* __restrict__ W1, const float* __restrict__ W2,
        unsigned short* __restrict__ W1T, unsigned short* __restrict__ W2T,
        const float* __restrict__ x, const float* __restrict__ Wr,
        const float* __restrict__ br, unsigned short* __restrict__ xb,
        int* __restrict__ topk_idx, float* __restrict__ topk_p)
{
    __shared__ float tile[128 * 64];
    int z = blockIdx.z;
    int tid = threadIdx.x;

    if (z == 16) {
        // router: 4 tokens/block (one per wave), fused x -> bf16 (r7 form)
        int wv = tid >> 6, lane = tid & 63;
        int t = blockIdx.x * 4 + wv;
        const float* xr = x + (size_t)t * DM;
        unsigned short* xbr = xb + (size_t)t * DM;
        float a0=0,a1=0,a2=0,a3=0,a4=0,a5=0,a6=0,a7=0;
        for (int d = lane; d < DM; d += 64) {
            float xv = xr[d];
            xbr[d] = f2bf(xv);
            const float4* wp = (const float4*)(Wr + d * 8);
            float4 w0 = wp[0], w1 = wp[1];
            a0 += xv * w0.x; a1 += xv * w0.y; a2 += xv * w0.z; a3 += xv * w0.w;
            a4 += xv * w1.x; a5 += xv * w1.y; a6 += xv * w1.z; a7 += xv * w1.w;
        }
#pragma unroll
        for (int off = 32; off; off >>= 1) {
            a0 += __shfl_xor(a0, off); a1 += __shfl_xor(a1, off);
            a2 += __shfl_xor(a2, off); a3 += __shfl_xor(a3, off);
            a4 += __shfl_xor(a4, off); a5 += __shfl_xor(a5, off);
            a6 += __shfl_xor(a6, off); a7 += __shfl_xor(a7, off);
        }
        if (lane == 0) {
            float l[8] = {a0 + br[0], a1 + br[1], a2 + br[2], a3 + br[3],
                          a4 + br[4], a5 + br[5], a6 + br[6], a7 + br[7]};
            int i0 = 0;
#pragma unroll
            for (int e = 1; e < 8; e++) if (l[e] > l[i0]) i0 = e;
            int i1 = (i0 == 0) ? 1 : 0;
#pragma unroll
            for (int e = 0; e < 8; e++) if (e != i0 && l[e] > l[i1]) i1 = e;
            float p1 = expf(l[i1] - l[i0]);
            float s = 1.0f + p1;
            topk_idx[2 * t]     = i0;
            topk_idx[2 * t + 1] = i1;
            topk_p[2 * t]       = 1.0f / s;
            topk_p[2 * t + 1]   = p1 / s;
        }
        return;
    }

    if (blockIdx.x >= 512) return;   // transpose layers use 512 blocks

    if (z < 8) {
        // W1 [1024 D][4096 F] -> W1T [4096 F][1024 D], expert z.
        // tiles: 8 (by over D, 128 rows) x 64 (bx over F, 64 cols)
        int bx = blockIdx.x & 63, by = blockIdx.x >> 6;
        transpose128x64(
            W1 + (size_t)z * DM * FF + (size_t)(by * 128) * FF + bx * 64, FF,
            W1T + (size_t)z * DM * FF + (size_t)(bx * 64) * DM + by * 128, DM,
            tile);
    } else {
        // W2 [4096 F][1024 D] -> W2T [1024 D][4096 F], expert z-8.
        // tiles: 32 (by over F, 128 rows) x 16 (bx over D, 64 cols)
        int e = z - 8;
        int bx = blockIdx.x & 15, by = blockIdx.x >> 4;
        transpose128x64(
            W2 + (size_t)e * FF * DM + (size_t)(by * 128) * DM + bx * 64, DM,
            W2T + (size_t)e * DM * FF + (size_t)(bx * 64) * FF + by * 128, FF,
            tile);
    }
}

// ---------------- route: histogram + prefix + scatter, one block ------------

__global__ __launch_bounds__(256) void k_route2(const int* __restrict__ topk_idx,
        int* __restrict__ cnt, int* __restrict__ offs,
        int* __restrict__ assign_tok, int* __restrict__ assign_e,
        int* __restrict__ slot)
{
    __shared__ int h[8], base[8];
    int tid = threadIdx.x;
    if (tid < 8) h[tid] = 0;
    __syncthreads();
    int el[32];
#pragma unroll
    for (int i = 0; i < 32; i++) {
        int idx = tid * 32 + i;
        el[i] = topk_idx[idx];
        atomicAdd(&h[el[i]], 1);
    }
    __syncthreads();
    if (tid == 0) {
        int s = 0;
        for (int e = 0; e < E_N; e++) { offs[e] = s; cnt[e] = h[e]; base[e] = s; s += h[e]; }
        offs[E_N] = s;
    }
    __syncthreads();
    if (tid < 8) h[tid] = base[tid];
    __syncthreads();
#pragma unroll
    for (int i = 0; i < 32; i++) {
        int idx = tid * 32 + i;
        int e = el[i];
        int pos = atomicAdd(&h[e], 1);
        assign_tok[pos] = idx >> 1;
        assign_e[pos] = e;
        slot[idx] = pos;
    }
}

// ---------------- persistent grouped GEMM, 128x128, 4 waves, m97 K-loop -----
// Block bid pinned to expert e = bid&7 (== its XCD). lb = bid>>3 in [0,128)
// strides the expert's tile list (y fastest -> consecutive blocks share a
// B panel in L2). Single 32KB LDS buffer, XOR swizzle, global_load_lds(16B),
// setprio around MFMA.

template<bool GATHER, bool EPI>
__global__ __launch_bounds__(256, 4) void k_gemm(
    const unsigned short* __restrict__ A,
    const unsigned short* __restrict__ BT,
    const float* __restrict__ bias,
    unsigned short* __restrict__ C,
    const int* __restrict__ cnt, const int* __restrict__ offs,
    const int* __restrict__ gather_tok,
    int Kslice, int N, int ldA, int ldB, int GX, int KS, size_t slicePitch)
{
    __shared__ __align__(1024) char lds[32768];   // A 16KB | B 16KB

    int bid = blockIdx.x;
    int e = bid & 7;                 // expert == XCD
    int lb = bid >> 3;
    int M = cnt[e];
    if (M <= 0) return;
    int off_e = offs[e];
    int nrows = (M + 127) >> 7;
    int ntiles = nrows * GX * KS;

    int tid = threadIdx.x;
    int wv = tid >> 6, lane = tid & 63;
    int lr = lane & 15, hi = lane >> 4;
    int mW = (wv >> 1) * 64, nW = (wv & 1) * 64;
    int colsw = ((lane & 7) ^ (lane >> 3)) * 8;
    int l3 = lane >> 3;
    int nt = Kslice >> 6;

    for (int t = lb; t < ntiles; t += NBX) {
        int r = t % nrows;
        int q = t / nrows;
        int xn = q % GX;
        int ks = q / GX;
        int m0 = r * 128;
        int n0 = xn * 128;
        int kbase = ks * Kslice;

        const unsigned short* aptr[4];
        const unsigned short* bptr[4];
#pragma unroll
        for (int i = 0; i < 4; i++) {
            int j = wv * 4 + i;
            int rr = m0 + j * 8 + l3; rr = (rr < M) ? rr : (M - 1);
            size_t arow = GATHER ? (size_t)gather_tok[off_e + rr] : (size_t)(off_e + rr);
            aptr[i] = A + arow * (size_t)ldA + kbase + colsw;
            int rb = n0 + j * 8 + l3;
            bptr[i] = BT + ((size_t)e * N + rb) * (size_t)ldB + kbase + colsw;
        }

        f32x4 acc[4][4];
        f32x4 zz = {0.f, 0.f, 0.f, 0.f};
#pragma unroll
        for (int mi = 0; mi < 4; mi++)
#pragma unroll
            for (int ni = 0; ni < 4; ni++) acc[mi][ni] = zz;

        for (int kt = 0; kt < nt; ++kt) {
            __syncthreads();                  // prev tile fully consumed
#pragma unroll
            for (int i = 0; i < 4; i++) {
                gload16(aptr[i] + kt * 64, (unsigned short*)(lds + (wv * 4 + i) * 1024));
                gload16(bptr[i] + kt * 64, (unsigned short*)(lds + 16384 + (wv * 4 + i) * 1024));
            }
            __syncthreads();                  // drains vmcnt before barrier
#pragma unroll
            for (int kss = 0; kss < 2; kss++) {
                int cb = (kss * 64 + hi * 16) ^ ((lr & 7) << 4);
                short8 afr[4], bfr[4];
#pragma unroll
                for (int ni = 0; ni < 4; ni++)
                    bfr[ni] = *(const short8*)(lds + 16384 + (nW + ni * 16 + lr) * 128 + cb);
#pragma unroll
                for (int mi = 0; mi < 4; mi++)
                    afr[mi] = *(const short8*)(lds + (mW + mi * 16 + lr) * 128 + cb);
                __builtin_amdgcn_s_setprio(1);
#pragma unroll
                for (int mi = 0; mi < 4; mi++)
#pragma unroll
                    for (int ni = 0; ni < 4; ni++)
                        acc[mi][ni] = __builtin_amdgcn_mfma_f32_16x16x32_bf16(
                            afr[mi], bfr[ni], acc[mi][ni], 0, 0, 0);
                __builtin_amdgcn_s_setprio(0);
            }
        }

        unsigned short* Cs = C + ks * slicePitch;
        float bv[4] = {0.f, 0.f, 0.f, 0.f};
        if (EPI) {
#pragma unroll
            for (int ni = 0; ni < 4; ni++)
                bv[ni] = bias[(size_t)e * N + (n0 + nW + ni * 16 + lr)];
        }
#pragma unroll
        for (int mi = 0; mi < 4; mi++) {
            int mb = m0 + mW + mi * 16 + hi * 4;
#pragma unroll
            for (int rr = 0; rr < 4; rr++) {
                int m = mb + rr;
                if (m < M) {
                    unsigned short* crow = Cs + (size_t)(off_e + m) * N;
#pragma unroll
                    for (int ni = 0; ni < 4; ni++) {
                        float v = acc[mi][ni][rr];
                        if (EPI) v = fmaxf(v + bv[ni], 0.0f);
                        crow[n0 + nW + ni * 16 + lr] = f2bf(v);
                    }
                }
            }
        }
    }
}

// ---------------- LN1 over F, in-place ----------------

__global__ __launch_bounds__(256) void k_ln1(unsigned short* __restrict__ H,
        const float* __restrict__ g, const float* __restrict__ b,
        const int* __restrict__ assign_e)
{
    size_t a = blockIdx.x;
    int e = assign_e[a];
    unsigned short* row = H + a * FF;
    int tid = threadIdx.x;
    uint4 u0 = *(const uint4*)(row + tid * 16);
    uint4 u1 = *(const uint4*)(row + tid * 16 + 8);
    float v[16];
    unp(u0.x, v[0], v[1]);  unp(u0.y, v[2], v[3]);
    unp(u0.z, v[4], v[5]);  unp(u0.w, v[6], v[7]);
    unp(u1.x, v[8], v[9]);  unp(u1.y, v[10], v[11]);
    unp(u1.z, v[12], v[13]); unp(u1.w, v[14], v[15]);
    float s = 0.f, q = 0.f;
#pragma unroll
    for (int i = 0; i < 16; i++) { s += v[i]; q += v[i] * v[i]; }
#pragma unroll
    for (int off = 32; off; off >>= 1) { s += __shfl_xor(s, off); q += __shfl_xor(q, off); }
    __shared__ float red[8];
    int wv = tid >> 6, lane = tid & 63;
    if (lane == 0) { red[wv * 2] = s; red[wv * 2 + 1] = q; }
    __syncthreads();
    s = red[0] + red[2] + red[4] + red[6];
    q = red[1] + red[3] + red[5] + red[7];
    float mu = s * (1.0f / FF);
    float var = q * (1.0f / FF) - mu * mu;
    float rstd = rsqrtf(var + LN_EPS);
    const float* gg = g + (size_t)e * FF + tid * 16;
    const float* bb = b + (size_t)e * FF + tid * 16;
    float4 G0 = *(const float4*)(gg);      float4 G1 = *(const float4*)(gg + 4);
    float4 G2 = *(const float4*)(gg + 8);  float4 G3 = *(const float4*)(gg + 12);
    float4 B0 = *(const float4*)(bb);      float4 B1 = *(const float4*)(bb + 4);
    float4 B2 = *(const float4*)(bb + 8);  float4 B3 = *(const float4*)(bb + 12);
    float gvv[16] = {G0.x,G0.y,G0.z,G0.w,G1.x,G1.y,G1.z,G1.w,G2.x,G2.y,G2.z,G2.w,G3.x,G3.y,G3.z,G3.w};
    float bvv[16] = {B0.x,B0.y,B0.z,B0.w,B1.x,B1.y,B1.z,B1.w,B2.x,B2.y,B2.z,B2.w,B3.x,B3.y,B3.z,B3.w};
#pragma unroll
    for (int i = 0; i < 16; i++) v[i] = (v[i] - mu) * rstd * gvv[i] + bvv[i];
    u0.x = pk(v[0], v[1]);  u0.y = pk(v[2], v[3]);
    u0.z = pk(v[4], v[5]);  u0.w = pk(v[6], v[7]);
    u1.x = pk(v[8], v[9]);  u1.y = pk(v[10], v[11]);
    u1.z = pk(v[12], v[13]); u1.w = pk(v[14], v[15]);
    *(uint4*)(row + tid * 16) = u0;
    *(uint4*)(row + tid * 16 + 8) = u1;
}

// ---------------- combine: sum split-K partials + bias + relu + LN2 + gate --

__global__ __launch_bounds__(256) void k_comb(const unsigned short* __restrict__ Yp,
        const float* __restrict__ g, const float* __restrict__ b2,
        const float* __restrict__ be,
        const int* __restrict__ slot, const float* __restrict__ topk_p,
        const int* __restrict__ assign_e, float* __restrict__ out)
{
    int t = blockIdx.x;
    int s0 = slot[2 * t], s1 = slot[2 * t + 1];
    float p0 = topk_p[2 * t], p1 = topk_p[2 * t + 1];
    int e0 = assign_e[s0], e1 = assign_e[s1];
    int tid = threadIdx.x;
    int d = tid * 4;
    const unsigned short* Y1 = Yp + (size_t)NA * DM;
    uint2 ua0 = *(const uint2*)(Yp + (size_t)s0 * DM + d);
    uint2 ua1 = *(const uint2*)(Y1 + (size_t)s0 * DM + d);
    uint2 ub0 = *(const uint2*)(Yp + (size_t)s1 * DM + d);
    uint2 ub1 = *(const uint2*)(Y1 + (size_t)s1 * DM + d);
    float4 bza = *(const float4*)(b2 + (size_t)e0 * DM + d);
    float4 bzb = *(const float4*)(b2 + (size_t)e1 * DM + d);
    float x0, x1, y0, y1;
    float va[4], vb[4];
    unp(ua0.x, x0, x1); unp(ua1.x, y0, y1);
    va[0] = fmaxf(x0 + y0 + bza.x, 0.f); va[1] = fmaxf(x1 + y1 + bza.y, 0.f);
    unp(ua0.y, x0, x1); unp(ua1.y, y0, y1);
    va[2] = fmaxf(x0 + y0 + bza.z, 0.f); va[3] = fmaxf(x1 + y1 + bza.w, 0.f);
    unp(ub0.x, x0, x1); unp(ub1.x, y0, y1);
    vb[0] = fmaxf(x0 + y0 + bzb.x, 0.f); vb[1] = fmaxf(x1 + y1 + bzb.y, 0.f);
    unp(ub0.y, x0, x1); unp(ub1.y, y0, y1);
    vb[2] = fmaxf(x0 + y0 + bzb.z, 0.f); vb[3] = fmaxf(x1 + y1 + bzb.w, 0.f);

    float sa = 0.f, qa = 0.f, sb = 0.f, qb = 0.f;
#pragma unroll
    for (int i = 0; i < 4; i++) {
        sa += va[i]; qa += va[i] * va[i];
        sb += vb[i]; qb += vb[i] * vb[i];
    }
#pragma unroll
    for (int off = 32; off; off >>= 1) {
        sa += __shfl_xor(sa, off); qa += __shfl_xor(qa, off);
        sb += __shfl_xor(sb, off); qb += __shfl_xor(qb, off);
    }
    __shared__ float red[16];
    int wv = tid >> 6, lane = tid & 63;
    if (lane == 0) { red[wv*4+0]=sa; red[wv*4+1]=qa; red[wv*4+2]=sb; red[wv*4+3]=qb; }
    __syncthreads();
    sa = red[0] + red[4] + red[8]  + red[12];
    qa = red[1] + red[5] + red[9]  + red[13];
    sb = red[2] + red[6] + red[10] + red[14];
    qb = red[3] + red[7] + red[11] + red[15];
    float mua = sa * (1.0f / DM), vara = qa * (1.0f / DM) - mua * mua;
    float ra = rsqrtf(vara + LN_EPS);
    float mub = sb * (1.0f / DM), varb = qb * (1.0f / DM) - mub * mub;
    float rb = rsqrtf(varb + LN_EPS);
    float4 ga  = *(const float4*)(g + (size_t)e0 * DM + d);
    float4 ba  = *(const float4*)(be + (size_t)e0 * DM + d);
    float4 gb4 = *(const float4*)(g + (size_t)e1 * DM + d);
    float4 bb4 = *(const float4*)(be + (size_t)e1 * DM + d);
    float4 o;
    o.x = p0 * ((va[0] - mua) * ra * ga.x + ba.x) + p1 * ((vb[0] - mub) * rb * gb4.x + bb4.x);
    o.y = p0 * ((va[1] - mua) * ra * ga.y + ba.y) + p1 * ((vb[1] - mub) * rb * gb4.y + bb4.y);
    o.z = p0 * ((va[2] - mua) * ra * ga.z + ba.z) + p1 * ((vb[2] - mub) * rb * gb4.z + bb4.z);
    o.w = p0 * ((va[3] - mua) * ra * ga.w + ba.w) + p1 * ((vb[3] - mub) * rb * gb4.w + bb4.w);
    *(float4*)(out + (size_t)t * DM + d) = o;
}

// ---------------- launch ----------------

extern "C" void kernel_launch(void* const* d_in, const int* in_sizes, int n_in,
                              void* d_out, int out_size, void* d_ws, size_t ws_size,
                              hipStream_t stream) {
    const float* x   = (const float*)d_in[0];
    const float* Wr  = (const float*)d_in[1];
    const float* br  = (const float*)d_in[2];
    const float* W1  = (const float*)d_in[3];
    const float* b1  = (const float*)d_in[4];
    const float* g1  = (const float*)d_in[5];
    const float* be1 = (const float*)d_in[6];
    const float* W2  = (const float*)d_in[7];
    const float* b2  = (const float*)d_in[8];
    const float* g2  = (const float*)d_in[9];
    const float* be2 = (const float*)d_in[10];
    float* out = (float*)d_out;

    char* w = (char*)d_ws;
    int*   cnt        = (int*)(w);
    int*   offs       = (int*)(w + 128);
    int*   topk_idx   = (int*)(w + 512);
    float* topk_p     = (float*)(w + 512 + (32 << 10));
    int*   assign_tok = (int*)(w + 512 + (64 << 10));
    int*   assign_e   = (int*)(w + 512 + (96 << 10));
    int*   slot       = (int*)(w + 512 + (128 << 10));
    unsigned short* xb  = (unsigned short*)(w + ((size_t)1 << 20));
    unsigned short* W1T = (unsigned short*)(w + ((size_t)9 << 20));    // [E][F][D] bf16
    unsigned short* W2T = (unsigned short*)(w + ((size_t)73 << 20));   // [E][D][F] bf16
    unsigned short* Hb  = (unsigned short*)(w + ((size_t)137 << 20));  // [NA][F] bf16
    unsigned short* Yp  = (unsigned short*)(w + ((size_t)201 << 20));  // [2][NA][D] bf16

    // prep: z 0..7 transpose W1, 8..15 transpose W2 (512 blocks each), 16 router
    k_prep<<<dim3(1024, 1, 17), 256, 0, stream>>>(
        W1, W2, W1T, W2T, x, Wr, br, xb, topk_idx, topk_p);
    k_route2<<<1, 256, 0, stream>>>(topk_idx, cnt, offs, assign_tok, assign_e, slot);
    // GEMM1: gathered x rows x W1T -> Hb(+bias,relu); K=1024, GX=32, KS=1
    k_gemm<true, true><<<8 * NBX, 256, 0, stream>>>(
        xb, W1T, b1, Hb, cnt, offs, assign_tok, DM, FF, DM, DM, 32, 1, 0);
    k_ln1<<<NA, 256, 0, stream>>>(Hb, g1, be1, assign_e);
    // GEMM2: Hb x W2T -> Yp partials; Kslice=2048, KS=2, GX=8
    k_gemm<false, false><<<8 * NBX, 256, 0, stream>>>(
        Hb, W2T, nullptr, Yp, cnt, offs, nullptr, FF / 2, DM, FF, FF, 8, 2,
        (size_t)NA * DM);
    k_comb<<<NTOK, 256, 0, stream>>>(Yp, g2, b2, be2, slot, topk_p, assign_e, out);
}